// Round 3
// baseline (253.303 us; speedup 1.0000x reference)
//
#include <hip/hip_runtime.h>
#include <math.h>

#define HH 256
#define WW 256
#define NF 4
#define NPHI 8
#define KSZ 9
#define PADW 272
#define PADH 264
#define RDSF 0.017453292519943295f
#define PIF  3.14159274101257324f

typedef float nvec4 __attribute__((ext_vector_type(4)));

// ---------------- pad: x (B,256,256) -> zero-bordered (B,264,272) ----------------
__global__ __launch_bounds__(256) void pad_kernel(const float* __restrict__ x,
                                                  float* __restrict__ pad, int B) {
    int idx = blockIdx.x * 256 + threadIdx.x;
    int tot = B * PADH * PADW;
    if (idx >= tot) return;
    int b  = idx / (PADH * PADW);
    int r  = idx % (PADH * PADW);
    int pr = r / PADW, pc = r % PADW;
    int ys = pr - 4, xs = pc - 4;
    float v = 0.0f;
    if (ys >= 0 && ys < HH && xs >= 0 && xs < WW)
        v = x[((size_t)b * HH + ys) * WW + xs];
    pad[idx] = v;
}

// coefficient for base kernel: ch = which*4+f, tap t=i*9+j
__device__ __forceinline__ float coef_val(int t, int ch, const float* l,
                                          const float* al, const float* be) {
    int which = ch >> 2, f = ch & 3;
    int i = t / 9, j = t % 9;
    float L = l[f], a = al[f], b = be[f];
    float xg = (float)j - 4.0f, yg = (float)i - 4.0f;
    float E = expf(-L * (a * xg * xg + b * yg * yg));
    if (which == 0) return -2.0f * a * L * L * xg / PIF * E;
    return -2.0f * b * L * L * yg / PIF * E;
}

// ---------------- coef: transposed layout coefT[t*8 + ch] ----------------
__global__ void coef_kernel(const float* __restrict__ l, const float* __restrict__ al,
                            const float* __restrict__ be, float* __restrict__ coefT) {
    int idx = blockIdx.x * blockDim.x + threadIdx.x;
    if (idx >= 81 * 8) return;
    coefT[idx] = coef_val(idx / 8, idx % 8, l, al, be);
}

// ---------------- conv: 8-channel 9x9 direct conv, 4 px per thread ----------------
// out layout: wsc[pixel*8 + ch], ch = which*4+f  (Cx f0..3, Cy f0..3)
__global__ __launch_bounds__(256) void conv_kernel(const float* __restrict__ pad,
                                                   const float* __restrict__ coefT,
                                                   float* __restrict__ wsc,
                                                   int b0, int nquad) {
    int g4 = blockIdx.x * 256 + threadIdx.x;
    if (g4 >= nquad) return;                 // nquad = npix/4
    const int QPI = HH * WW / 4;             // quads per image
    int bl = g4 / QPI;
    int p  = (g4 % QPI) * 4;                 // chunk-local pixel (multiple of 4)
    int yy = p / WW, xx = p % WW;            // xx multiple of 4
    const float* pb = pad + ((size_t)(b0 + bl) * PADH + yy) * PADW + xx;

    float acc[4][8];
#pragma unroll
    for (int px = 0; px < 4; ++px)
#pragma unroll
        for (int ch = 0; ch < 8; ++ch) acc[px][ch] = 0.0f;

#pragma unroll
    for (int i = 0; i < 9; ++i) {
        const float4* r4 = reinterpret_cast<const float4*>(pb + i * PADW);  // 16B-aligned
        float4 A = r4[0], Bv = r4[1], Cv = r4[2];
        float w[12] = {A.x, A.y, A.z, A.w, Bv.x, Bv.y, Bv.z, Bv.w, Cv.x, Cv.y, Cv.z, Cv.w};
#pragma unroll
        for (int j = 0; j < 9; ++j) {
            const float4* cc = reinterpret_cast<const float4*>(coefT + (i * 9 + j) * 8);
            float4 c0 = cc[0], c1 = cc[1];   // wave-uniform, L1-broadcast
#pragma unroll
            for (int px = 0; px < 4; ++px) {
                float wv = w[px + j];
                acc[px][0] = fmaf(wv, c0.x, acc[px][0]);
                acc[px][1] = fmaf(wv, c0.y, acc[px][1]);
                acc[px][2] = fmaf(wv, c0.z, acc[px][2]);
                acc[px][3] = fmaf(wv, c0.w, acc[px][3]);
                acc[px][4] = fmaf(wv, c1.x, acc[px][4]);
                acc[px][5] = fmaf(wv, c1.y, acc[px][5]);
                acc[px][6] = fmaf(wv, c1.z, acc[px][6]);
                acc[px][7] = fmaf(wv, c1.w, acc[px][7]);
            }
        }
    }
    float* o = wsc + (size_t)g4 * 32;        // 4 px * 8 ch, contiguous per thread
#pragma unroll
    for (int px = 0; px < 4; ++px) {
        *reinterpret_cast<float4*>(o + px * 8)     = make_float4(acc[px][0], acc[px][1], acc[px][2], acc[px][3]);
        *reinterpret_cast<float4*>(o + px * 8 + 4) = make_float4(acc[px][4], acc[px][5], acc[px][6], acc[px][7]);
    }
}

// ---------------- rotate + angle-combine ----------------
// out[b,phi,r,c,f] = cos(th)*Bilerp(Cx_f) + sin(th)*Bilerp(Cy_f), zero fill OOB
__global__ __launch_bounds__(256) void rot_kernel(const float* __restrict__ wsc,
                                                  float* __restrict__ out,
                                                  int b0, int nb) {
    // XCD-aware bijective swizzle: grid = nb*8*256 (always %8==0). Each XCD
    // gets a contiguous chunk (~2 images of conv data ≈ 4.2MB ≈ its L2).
    int nwg  = gridDim.x;
    int orig = blockIdx.x;
    int blk  = (orig & 7) * (nwg >> 3) + (orig >> 3);

    int yy  = blk % HH; blk /= HH;
    int phi = blk % NPHI; blk /= NPHI;
    int bl  = blk;
    int b   = b0 + bl;
    int xx  = threadIdx.x;

    float theta = (float)(phi * 45) * RDSF;
    float st = sinf(theta), ct = cosf(theta);

    float fx = (float)xx - 127.5f;
    float fy = (float)yy - 127.5f;
    float xi = ct * fx - st * fy + 127.5f;
    float yi = st * fx + ct * fy + 127.5f;
    float x0f = floorf(xi), y0f = floorf(yi);
    float wx = xi - x0f, wy = yi - y0f;
    int x0 = (int)x0f, y0 = (int)y0f;

    float cx0 = 0.f, cx1 = 0.f, cx2 = 0.f, cx3 = 0.f;
    float cy0 = 0.f, cy1 = 0.f, cy2 = 0.f, cy3 = 0.f;
    const float* base = wsc + (size_t)bl * (HH * WW * 8);

    auto tap = [&](int ty, int tx, float w) {
        if (ty < 0 || ty >= HH || tx < 0 || tx >= WW) return;
        const float* p = base + ((size_t)ty * WW + tx) * 8;
        float4 vx = *reinterpret_cast<const float4*>(p);
        float4 vy = *reinterpret_cast<const float4*>(p + 4);
        cx0 = fmaf(w, vx.x, cx0); cx1 = fmaf(w, vx.y, cx1);
        cx2 = fmaf(w, vx.z, cx2); cx3 = fmaf(w, vx.w, cx3);
        cy0 = fmaf(w, vy.x, cy0); cy1 = fmaf(w, vy.y, cy1);
        cy2 = fmaf(w, vy.z, cy2); cy3 = fmaf(w, vy.w, cy3);
    };
    tap(y0,     x0,     (1.f - wy) * (1.f - wx));
    tap(y0,     x0 + 1, (1.f - wy) * wx);
    tap(y0 + 1, x0,     wy * (1.f - wx));
    tap(y0 + 1, x0 + 1, wy * wx);

    nvec4 r = {ct * cx0 + st * cy0, ct * cx1 + st * cy1,
               ct * cx2 + st * cy2, ct * cx3 + st * cy3};
    size_t oidx = ((((size_t)b * NPHI + phi) * HH + yy) * WW + xx) * NF;
    // write-once stream: nontemporal keeps conv intermediate resident in cache
    __builtin_nontemporal_store(r, reinterpret_cast<nvec4*>(out + oidx));
}

// ---------------- fallback: fully fused, ZERO workspace use ----------------
// Only used if ws_size is too small for the staged path. Correctness > speed.
__global__ __launch_bounds__(256) void fused_fallback_kernel(
        const float* __restrict__ x, const float* __restrict__ l,
        const float* __restrict__ al, const float* __restrict__ be,
        float* __restrict__ out) {
    __shared__ float sc[81 * 8];             // coefT[t*8+ch]
    for (int idx = threadIdx.x; idx < 81 * 8; idx += 256)
        sc[idx] = coef_val(idx / 8, idx % 8, l, al, be);
    __syncthreads();

    int blk = blockIdx.x;
    int yy  = blk % HH; blk /= HH;
    int phi = blk % NPHI; blk /= NPHI;
    int b   = blk;
    int xx  = threadIdx.x;

    float theta = (float)(phi * 45) * RDSF;
    float st = sinf(theta), ct = cosf(theta);
    float fx = (float)xx - 127.5f;
    float fy = (float)yy - 127.5f;
    float xi = ct * fx - st * fy + 127.5f;
    float yi = st * fx + ct * fy + 127.5f;
    float x0f = floorf(xi), y0f = floorf(yi);
    float wx = xi - x0f, wy = yi - y0f;
    int x0 = (int)x0f, y0 = (int)y0f;

    float cx[4] = {0, 0, 0, 0}, cy[4] = {0, 0, 0, 0};
    const float* xb = x + (size_t)b * HH * WW;

    for (int tp = 0; tp < 4; ++tp) {
        int ty = y0 + (tp >> 1), tx = x0 + (tp & 1);
        float w = ((tp >> 1) ? wy : 1.f - wy) * ((tp & 1) ? wx : 1.f - wx);
        if (ty < 0 || ty >= HH || tx < 0 || tx >= WW || w == 0.f) continue;
        float a[8] = {0, 0, 0, 0, 0, 0, 0, 0};
        for (int i = 0; i < 9; ++i) {
            int sy = ty + i - 4;
            if (sy < 0 || sy >= HH) continue;
            for (int j = 0; j < 9; ++j) {
                int sx = tx + j - 4;
                if (sx < 0 || sx >= WW) continue;
                float v = xb[sy * WW + sx];
                const float* c = sc + (i * 9 + j) * 8;
#pragma unroll
                for (int ch = 0; ch < 8; ++ch) a[ch] = fmaf(v, c[ch], a[ch]);
            }
        }
#pragma unroll
        for (int f = 0; f < 4; ++f) {
            cx[f] = fmaf(w, a[f], cx[f]);
            cy[f] = fmaf(w, a[4 + f], cy[f]);
        }
    }
    size_t oidx = ((((size_t)b * NPHI + phi) * HH + yy) * WW + xx) * NF;
#pragma unroll
    for (int f = 0; f < 4; ++f) out[oidx + f] = ct * cx[f] + st * cy[f];
}

extern "C" void kernel_launch(void* const* d_in, const int* in_sizes, int n_in,
                              void* d_out, int out_size, void* d_ws, size_t ws_size,
                              hipStream_t stream) {
    const float* x  = (const float*)d_in[0];
    const float* l  = (const float*)d_in[1];
    const float* al = (const float*)d_in[2];
    const float* be = (const float*)d_in[3];
    float* out = (float*)d_out;
    float* ws  = (float*)d_ws;

    int B = in_sizes[0] / (HH * WW);

    // ws layout (floats): [pad: B*264*272][coef: 648][align][conv: chunk*H*W*8]
    size_t padElems = (size_t)B * PADH * PADW;           // multiple of 4 -> 16B aligned
    size_t coefOff  = padElems;
    size_t convOff  = (padElems + 648 + 3) & ~(size_t)3; // 16B-align
    size_t wsFloats = ws_size / 4;
    size_t perBatch = (size_t)HH * WW * 8;

    if (convOff + perBatch > wsFloats) {
        // workspace can't stage even one image -> fused zero-ws fallback
        fused_fallback_kernel<<<B * NPHI * HH, 256, 0, stream>>>(x, l, al, be, out);
        return;
    }

    int chunk = B;
    if (convOff + (size_t)B * perBatch > wsFloats) {
        size_t cap = (wsFloats - convOff) / perBatch;
        chunk = (int)cap;
        if (chunk > B) chunk = B;
    }

    float* padBuf  = ws;
    float* coefBuf = ws + coefOff;
    float* convBuf = ws + convOff;

    int padTot = B * PADH * PADW;
    pad_kernel<<<(padTot + 255) / 256, 256, 0, stream>>>(x, padBuf, B);
    coef_kernel<<<3, 256, 0, stream>>>(l, al, be, coefBuf);

    for (int b0 = 0; b0 < B; b0 += chunk) {
        int nb = (B - b0 < chunk) ? (B - b0) : chunk;
        int nquad = nb * (HH * WW / 4);
        conv_kernel<<<(nquad + 255) / 256, 256, 0, stream>>>(padBuf, coefBuf, convBuf, b0, nquad);
        rot_kernel<<<nb * NPHI * HH, 256, 0, stream>>>(convBuf, out, b0, nb);
    }
}

// Round 10
// 202.621 us; speedup vs baseline: 1.2501x; 1.2501x over previous
//
#include <hip/hip_runtime.h>
#include <math.h>

#define HH 256
#define WW 256
#define NF 4
#define NPHI 8
#define KSZ 9
#define PADW 272
#define PADH 264
#define RDSF 0.017453292519943295f
#define PIF  3.14159274101257324f

typedef float nvec4 __attribute__((ext_vector_type(4)));

// ---------------- pad: x (B,256,256) -> zero-bordered (B,264,272) ----------------
__global__ __launch_bounds__(256) void pad_kernel(const float* __restrict__ x,
                                                  float* __restrict__ pad, int B) {
    int idx = blockIdx.x * 256 + threadIdx.x;
    int tot = B * PADH * PADW;
    if (idx >= tot) return;
    int b  = idx / (PADH * PADW);
    int r  = idx % (PADH * PADW);
    int pr = r / PADW, pc = r % PADW;
    int ys = pr - 4, xs = pc - 4;
    float v = 0.0f;
    if (ys >= 0 && ys < HH && xs >= 0 && xs < WW)
        v = x[((size_t)b * HH + ys) * WW + xs];
    pad[idx] = v;
}

// coefficient for base kernel: ch = which*4+f, tap t=i*9+j
__device__ __forceinline__ float coef_val(int t, int ch, const float* l,
                                          const float* al, const float* be) {
    int which = ch >> 2, f = ch & 3;
    int i = t / 9, j = t % 9;
    float L = l[f], a = al[f], b = be[f];
    float xg = (float)j - 4.0f, yg = (float)i - 4.0f;
    float E = expf(-L * (a * xg * xg + b * yg * yg));
    if (which == 0) return -2.0f * a * L * L * xg / PIF * E;
    return -2.0f * b * L * L * yg / PIF * E;
}

// ---------------- conv: 8-channel 9x9 direct conv, 4 px per thread ----------------
// coef computed into LDS per block (uniform-addr ds_read broadcasts, no VMEM)
// out layout: wsc[pixel*8 + ch], ch = which*4+f  (Cx f0..3, Cy f0..3)
__global__ __launch_bounds__(256) void conv_kernel(const float* __restrict__ pad,
                                                   const float* __restrict__ l,
                                                   const float* __restrict__ al,
                                                   const float* __restrict__ be,
                                                   float* __restrict__ wsc,
                                                   int b0, int nquad) {
    __shared__ float sc[81 * 8];             // sc[t*8+ch]
    for (int idx = threadIdx.x; idx < 81 * 8; idx += 256)
        sc[idx] = coef_val(idx / 8, idx % 8, l, al, be);
    __syncthreads();

    int g4 = blockIdx.x * 256 + threadIdx.x;
    if (g4 >= nquad) return;                 // nquad = npix/4
    const int QPI = HH * WW / 4;             // quads per image
    int bl = g4 / QPI;
    int p  = (g4 % QPI) * 4;                 // chunk-local pixel (multiple of 4)
    int yy = p / WW, xx = p % WW;            // xx multiple of 4
    const float* pb = pad + ((size_t)(b0 + bl) * PADH + yy) * PADW + xx;

    float acc[4][8];
#pragma unroll
    for (int px = 0; px < 4; ++px)
#pragma unroll
        for (int ch = 0; ch < 8; ++ch) acc[px][ch] = 0.0f;

    // keep the i-loop rolled: hot body ~2.5KB (I-cache friendly); j/px/ch static
#pragma unroll 1
    for (int i = 0; i < 9; ++i) {
        const float4* r4 = reinterpret_cast<const float4*>(pb + i * PADW);  // 16B-aligned
        float4 A = r4[0], Bv = r4[1], Cv = r4[2];
        float w[12] = {A.x, A.y, A.z, A.w, Bv.x, Bv.y, Bv.z, Bv.w, Cv.x, Cv.y, Cv.z, Cv.w};
        const float* scrow = sc + i * 9 * 8;
#pragma unroll
        for (int j = 0; j < 9; ++j) {
            const float4* cc = reinterpret_cast<const float4*>(scrow + j * 8);
            float4 c0 = cc[0], c1 = cc[1];   // uniform addr -> LDS broadcast
#pragma unroll
            for (int px = 0; px < 4; ++px) {
                float wv = w[px + j];
                acc[px][0] = fmaf(wv, c0.x, acc[px][0]);
                acc[px][1] = fmaf(wv, c0.y, acc[px][1]);
                acc[px][2] = fmaf(wv, c0.z, acc[px][2]);
                acc[px][3] = fmaf(wv, c0.w, acc[px][3]);
                acc[px][4] = fmaf(wv, c1.x, acc[px][4]);
                acc[px][5] = fmaf(wv, c1.y, acc[px][5]);
                acc[px][6] = fmaf(wv, c1.z, acc[px][6]);
                acc[px][7] = fmaf(wv, c1.w, acc[px][7]);
            }
        }
    }
    float* o = wsc + (size_t)g4 * 32;        // 4 px * 8 ch, contiguous per thread
#pragma unroll
    for (int px = 0; px < 4; ++px) {
        *reinterpret_cast<float4*>(o + px * 8)     = make_float4(acc[px][0], acc[px][1], acc[px][2], acc[px][3]);
        *reinterpret_cast<float4*>(o + px * 8 + 4) = make_float4(acc[px][4], acc[px][5], acc[px][6], acc[px][7]);
    }
}

// ---------------- rotate + angle-combine, LDS-tiled ----------------
// Each block: 16x16 output tile of one (b,phi). Stage rotated-bbox footprint of
// the conv intermediate into LDS (coalesced), gather bilinear taps from LDS.
// out[b,phi,r,c,f] = cos(th)*Bilerp(Cx_f) + sin(th)*Bilerp(Cy_f), zero fill OOB
__global__ __launch_bounds__(256) void rot_tiled_kernel(const float* __restrict__ wsc,
                                                        float* __restrict__ out,
                                                        int b0, int nb) {
    // two float4 planes, capacity 624 px (= 24 rows x 26 stride) = 19.5 KB
    __shared__ nvec4 ldsX[624];
    __shared__ nvec4 ldsY[624];

    // XCD-aware bijective swizzle (grid = nb*2048, always %8==0):
    // each XCD gets a contiguous chunk = 2 images of conv data = 4MB = its L2
    int nwg  = gridDim.x;
    int orig = blockIdx.x;
    int blk  = (orig & 7) * (nwg >> 3) + (orig >> 3);

    int txt = blk & 15; blk >>= 4;           // tile x
    int tyt = blk & 15; blk >>= 4;           // tile y
    int phi = blk & 7;  blk >>= 3;
    int bl  = blk;

    float theta = (float)(phi * 45) * RDSF;
    float st = sinf(theta), ct = cosf(theta);

    // per-phi LDS row stride keeps the lane-walk step coprime-ish with banks
    int SW = (phi & 1) ? 26 : 25;
    int NYCAP = 624 / SW;

    int X0 = txt * 16, Y0 = tyt * 16;
    // footprint bbox from tile corner source coords (xi/yi affine in fx,fy)
    float fxa = (float)X0 - 127.5f, fxb = fxa + 15.0f;
    float fya = (float)Y0 - 127.5f, fyb = fya + 15.0f;
    float c1 = ct * fxa, c2 = ct * fxb, s1 = st * fya, s2 = st * fyb;
    float xmin = fminf(c1, c2) - fmaxf(s1, s2) + 127.5f;
    float xmax = fmaxf(c1, c2) - fminf(s1, s2) + 127.5f;
    float t1 = st * fxa, t2 = st * fxb, u1 = ct * fya, u2 = ct * fyb;
    float ymin = fminf(t1, t2) + fminf(u1, u2) + 127.5f;
    float ymax = fmaxf(t1, t2) + fmaxf(u1, u2) + 127.5f;

    int gx0 = max(0, (int)floorf(xmin));
    int gx1 = min(WW - 1, (int)floorf(xmax) + 1);
    int gy0 = max(0, (int)floorf(ymin));
    int gy1 = min(HH - 1, (int)floorf(ymax) + 1);
    // Footprint fully outside the image gives gx1<gx0 (nx<0). MUST clamp to 0:
    // the unsigned tap guard below would otherwise admit every tap against
    // uninitialized LDS (this was R8's absmax=322 failure). nx=0/ny=0 rejects
    // all taps -> zero output = reference zero-fill.
    int nx = min(max(gx1 - gx0 + 1, 0), SW);
    int ny = min(max(gy1 - gy0 + 1, 0), NYCAP);

    const float* src = wsc + (size_t)bl * (HH * WW * 8);
    int tot = ny * nx;
    for (int idx = threadIdx.x; idx < tot; idx += 256) {
        int r = idx / nx, c = idx - r * nx;
        const float* p = src + (((size_t)(gy0 + r)) * WW + (gx0 + c)) * 8;
        ldsX[r * SW + c] = *reinterpret_cast<const nvec4*>(p);
        ldsY[r * SW + c] = *reinterpret_cast<const nvec4*>(p + 4);
    }
    __syncthreads();

    int xx = X0 + (threadIdx.x & 15);
    int yy = Y0 + (threadIdx.x >> 4);
    float fx = (float)xx - 127.5f;
    float fy = (float)yy - 127.5f;
    float xi = ct * fx - st * fy + 127.5f;
    float yi = st * fx + ct * fy + 127.5f;
    float x0f = floorf(xi), y0f = floorf(yi);
    float wx = xi - x0f, wy = yi - y0f;
    int x0 = (int)x0f, y0 = (int)y0f;

    nvec4 ax = {0.f, 0.f, 0.f, 0.f};
    nvec4 ay = {0.f, 0.f, 0.f, 0.f};
    // Guard against the STAGED range (= bbox ∩ image, subset of image range):
    // every admitted tap matches reference semantics; a tap rejected only by a
    // 1-ULP bbox/pixel fp mismatch provably carries ~ULP-scale weight. Also
    // makes a negative/OOB LDS index impossible.
    auto tap = [&](int tyy, int txx, float w) {
        int ly = tyy - gy0, lx = txx - gx0;
        if ((unsigned)ly >= (unsigned)ny || (unsigned)lx >= (unsigned)nx) return;
        int p = ly * SW + lx;
        ax += w * ldsX[p];
        ay += w * ldsY[p];
    };
    tap(y0,     x0,     (1.f - wy) * (1.f - wx));
    tap(y0,     x0 + 1, (1.f - wy) * wx);
    tap(y0 + 1, x0,     wy * (1.f - wx));
    tap(y0 + 1, x0 + 1, wy * wx);

    nvec4 r = ct * ax + st * ay;
    size_t oidx = ((((size_t)(b0 + bl) * NPHI + phi) * HH + yy) * WW + xx) * NF;
    // write-once stream: nontemporal keeps conv intermediate resident in cache
    __builtin_nontemporal_store(r, reinterpret_cast<nvec4*>(out + oidx));
}

// ---------------- fallback: fully fused, ZERO workspace use ----------------
__global__ __launch_bounds__(256) void fused_fallback_kernel(
        const float* __restrict__ x, const float* __restrict__ l,
        const float* __restrict__ al, const float* __restrict__ be,
        float* __restrict__ out) {
    __shared__ float sc[81 * 8];             // sc[t*8+ch]
    for (int idx = threadIdx.x; idx < 81 * 8; idx += 256)
        sc[idx] = coef_val(idx / 8, idx % 8, l, al, be);
    __syncthreads();

    int blk = blockIdx.x;
    int yy  = blk % HH; blk /= HH;
    int phi = blk % NPHI; blk /= NPHI;
    int b   = blk;
    int xx  = threadIdx.x;

    float theta = (float)(phi * 45) * RDSF;
    float st = sinf(theta), ct = cosf(theta);
    float fx = (float)xx - 127.5f;
    float fy = (float)yy - 127.5f;
    float xi = ct * fx - st * fy + 127.5f;
    float yi = st * fx + ct * fy + 127.5f;
    float x0f = floorf(xi), y0f = floorf(yi);
    float wx = xi - x0f, wy = yi - y0f;
    int x0 = (int)x0f, y0 = (int)y0f;

    float cx[4] = {0, 0, 0, 0}, cy[4] = {0, 0, 0, 0};
    const float* xb = x + (size_t)b * HH * WW;

    for (int tp = 0; tp < 4; ++tp) {
        int ty = y0 + (tp >> 1), tx = x0 + (tp & 1);
        float w = ((tp >> 1) ? wy : 1.f - wy) * ((tp & 1) ? wx : 1.f - wx);
        if (ty < 0 || ty >= HH || tx < 0 || tx >= WW || w == 0.f) continue;
        float a[8] = {0, 0, 0, 0, 0, 0, 0, 0};
        for (int i = 0; i < 9; ++i) {
            int sy = ty + i - 4;
            if (sy < 0 || sy >= HH) continue;
            for (int j = 0; j < 9; ++j) {
                int sx = tx + j - 4;
                if (sx < 0 || sx >= WW) continue;
                float v = xb[sy * WW + sx];
                const float* c = sc + (i * 9 + j) * 8;
#pragma unroll
                for (int ch = 0; ch < 8; ++ch) a[ch] = fmaf(v, c[ch], a[ch]);
            }
        }
#pragma unroll
        for (int f = 0; f < 4; ++f) {
            cx[f] = fmaf(w, a[f], cx[f]);
            cy[f] = fmaf(w, a[4 + f], cy[f]);
        }
    }
    size_t oidx = ((((size_t)b * NPHI + phi) * HH + yy) * WW + xx) * NF;
#pragma unroll
    for (int f = 0; f < 4; ++f) out[oidx + f] = ct * cx[f] + st * cy[f];
}

extern "C" void kernel_launch(void* const* d_in, const int* in_sizes, int n_in,
                              void* d_out, int out_size, void* d_ws, size_t ws_size,
                              hipStream_t stream) {
    const float* x  = (const float*)d_in[0];
    const float* l  = (const float*)d_in[1];
    const float* al = (const float*)d_in[2];
    const float* be = (const float*)d_in[3];
    float* out = (float*)d_out;
    float* ws  = (float*)d_ws;

    int B = in_sizes[0] / (HH * WW);

    // ws layout (floats): [pad: B*264*272][conv: chunk*H*W*8]
    size_t padElems = (size_t)B * PADH * PADW;   // multiple of 4 -> 16B aligned
    size_t convOff  = padElems;
    size_t wsFloats = ws_size / 4;
    size_t perBatch = (size_t)HH * WW * 8;

    if (convOff + perBatch > wsFloats) {
        // workspace can't stage even one image -> fused zero-ws fallback
        fused_fallback_kernel<<<B * NPHI * HH, 256, 0, stream>>>(x, l, al, be, out);
        return;
    }

    int chunk = B;
    if (convOff + (size_t)B * perBatch > wsFloats) {
        size_t cap = (wsFloats - convOff) / perBatch;
        chunk = (int)cap;
        if (chunk > B) chunk = B;
    }

    float* padBuf  = ws;
    float* convBuf = ws + convOff;

    int padTot = B * PADH * PADW;
    pad_kernel<<<(padTot + 255) / 256, 256, 0, stream>>>(x, padBuf, B);

    for (int b0 = 0; b0 < B; b0 += chunk) {
        int nb = (B - b0 < chunk) ? (B - b0) : chunk;
        int nquad = nb * (HH * WW / 4);
        conv_kernel<<<(nquad + 255) / 256, 256, 0, stream>>>(padBuf, l, al, be, convBuf, b0, nquad);
        rot_tiled_kernel<<<nb * NPHI * 256, 256, 0, stream>>>(convBuf, out, b0, nb);
    }
}